// Round 3
// baseline (454.868 us; speedup 1.0000x reference)
//
#include <hip/hip_runtime.h>
#include <math.h>

// Multi-class SVM hinge loss + correct-count. Streaming, memory-bound:
// 262 MB mandatory read -> ~40 us floor at 6.6 TB/s.
//  - lane-local hinge accumulation across rows, one wave reduce at the end
//  - accuracy via per-row __ballot of "violation" (argmax==label iff none)
//  - labels+grounds prefetched in parallel, broadcast via __shfl
//  - C==1000 specialization: exactly 3 uniform + 1 predicated float4 load
//    per lane per row, issued back-to-back -> 4 loads in flight per wave
//    (Little's law: 32 waves/CU x 64 B ~ 2 KB in flight ~ 6 TB/s)
//  - fused finalize: last-block-done via counter in d_ws (memset to 0 each
//    launch; d_ws is re-poisoned 0xAA so we cannot rely on prior state)

#define BLOCK 256
#define GRID1 2048
#define WPB   (BLOCK / 64)            // 4 waves per block
#define NWAVE (GRID1 * WPB)           // 8192 waves = 32/CU

__global__ __launch_bounds__(BLOCK) void msrp_fused(
    const float* __restrict__ outp, const int* __restrict__ labels,
    float* __restrict__ partS, int* __restrict__ partC,
    unsigned int* __restrict__ counter, float* __restrict__ dst,
    int B, int C) {
  const int lane    = threadIdx.x & 63;
  const int wib     = threadIdx.x >> 6;
  const int wave_id = blockIdx.x * WPB + wib;
  const int R       = (B + NWAVE - 1) / NWAVE;   // rows per wave (8)
  const int r0      = wave_id * R;

  // Parallel prefetch: lane k holds row r0+k's label and ground score.
  int   mylab = 0;
  float myg   = 0.0f;
  if (lane < R && lane < 64 && r0 + lane < B) {
    mylab = labels[r0 + lane];
    myg   = outp[(size_t)(r0 + lane) * C + mylab];
  }

  float s0 = 0.f, s1 = 0.f, s2 = 0.f, s3 = 0.f;  // 4 accumulators for ILP
  int correct = 0;                                // lane 0 only

#define CONSUME(v, jb)                                                   \
  do {                                                                   \
    s0 += fmaxf((v).x + base, 0.0f);                                     \
    s1 += fmaxf((v).y + base, 0.0f);                                     \
    s2 += fmaxf((v).z + base, 0.0f);                                     \
    s3 += fmaxf((v).w + base, 0.0f);                                     \
    viol |= ((v).x > g) | (((v).x == g) & ((jb)     < label));           \
    viol |= ((v).y > g) | (((v).y == g) & ((jb) + 1 < label));           \
    viol |= ((v).z > g) | (((v).z == g) & ((jb) + 2 < label));           \
    viol |= ((v).w > g) | (((v).w == g) & ((jb) + 3 < label));           \
  } while (0)

  if (C == 1000) {
    // 250 float4 per row: lanes 0..63 cover j = lane, lane+64, lane+128;
    // lanes 0..57 additionally j = lane+192 (total 192+58 = 250).
    for (int k = 0; k < R; ++k) {
      const int row = r0 + k;
      if (row >= B) break;
      const int   label = (R <= 64) ? __shfl(mylab, k, 64) : labels[row];
      const float g     = (R <= 64) ? __shfl(myg, k, 64)
                                    : outp[(size_t)row * C + label];
      const float base  = 1.0f - g;
      const float4* rp4 = (const float4*)(outp + (size_t)row * 1000);

      // issue all loads back-to-back before any consumption
      float4 v0 = rp4[lane];
      float4 v1 = rp4[lane + 64];
      float4 v2 = rp4[lane + 128];
      const bool h3 = (lane < 58);
      float4 v3;
      if (h3) v3 = rp4[lane + 192];

      bool viol = false;
      CONSUME(v0, lane * 4);
      CONSUME(v1, (lane + 64) * 4);
      CONSUME(v2, (lane + 128) * 4);
      if (h3) CONSUME(v3, (lane + 192) * 4);

      const unsigned long long m = __ballot(viol);
      if (lane == 0) correct += (m == 0ULL) ? 1 : 0;
    }
  } else {
    const int C4 = C >> 2;
    for (int k = 0; k < R; ++k) {
      const int row = r0 + k;
      if (row >= B) break;
      const int   label = (R <= 64) ? __shfl(mylab, k, 64) : labels[row];
      const float g     = (R <= 64) ? __shfl(myg, k, 64)
                                    : outp[(size_t)row * C + label];
      const float base  = 1.0f - g;
      const float4* rp4 = (const float4*)(outp + (size_t)row * C);
      bool viol = false;
      for (int j = lane; j < C4; j += 64) {
        float4 v = rp4[j];
        CONSUME(v, j << 2);
      }
      const float* rowp = (const float*)rp4;
      for (int j = (C4 << 2) + lane; j < C; j += 64) {
        float v = rowp[j];
        s0 += fmaxf(v + base, 0.0f);
        viol |= (v > g) | ((v == g) & (j < label));
      }
      const unsigned long long m = __ballot(viol);
      if (lane == 0) correct += (m == 0ULL) ? 1 : 0;
    }
  }
#undef CONSUME

  // wave reduction of the hinge sum
  float s = (s0 + s1) + (s2 + s3);
  for (int off = 32; off > 0; off >>= 1) s += __shfl_down(s, off, 64);

  __shared__ float ls[WPB];
  __shared__ int   cs[WPB];
  __shared__ bool  amLast;
  if (lane == 0) { ls[wib] = s; cs[wib] = correct; }
  __syncthreads();
  if (threadIdx.x == 0) {
    float S = 0.f; int cc = 0;
    for (int w = 0; w < WPB; ++w) { S += ls[w]; cc += cs[w]; }
    partS[blockIdx.x] = S;
    partC[blockIdx.x] = cc;
    __threadfence();                          // publish partials (device scope)
    const unsigned int old = atomicAdd(counter, 1u);
    amLast = (old == (unsigned)GRID1 - 1u);
  }
  __syncthreads();

  if (amLast) {                               // block-uniform
    __threadfence();                          // acquire: see all partials
    float fs = 0.f; int fc = 0;
    for (int i = threadIdx.x; i < GRID1; i += BLOCK) {
      fs += partS[i];
      fc += partC[i];
    }
    for (int off = 32; off > 0; off >>= 1) {
      fs += __shfl_down(fs, off, 64);
      fc += __shfl_down(fc, off, 64);
    }
    if (lane == 0) { ls[wib] = fs; cs[wib] = fc; }
    __syncthreads();
    if (threadIdx.x == 0) {
      float S = 0.f; int cc = 0;
      for (int w = 0; w < WPB; ++w) { S += ls[w]; cc += cs[w]; }
      // loss = (S_total - B)/B = S/B - 1 (per-row "-1" folded in)
      dst[0] = S / (float)B - 1.0f;
      dst[1] = (float)cc;
    }
  }
}

extern "C" void kernel_launch(void* const* d_in, const int* in_sizes, int n_in,
                              void* d_out, int out_size, void* d_ws, size_t ws_size,
                              hipStream_t stream) {
  const float* outp   = (const float*)d_in[0];
  const int*   labels = (const int*)d_in[1];
  float*       dst    = (float*)d_out;

  const int B = in_sizes[1];
  const int C = in_sizes[0] / B;

  float*        partS   = (float*)d_ws;                 // GRID1 floats
  int*          partC   = (int*)(partS + GRID1);        // GRID1 ints
  unsigned int* counter = (unsigned int*)(partC + GRID1);

  // d_ws is re-poisoned to 0xAA before every timed launch; the last-block
  // counter must start at 0 (async 4-byte memset is graph-capture safe).
  hipMemsetAsync(counter, 0, sizeof(unsigned int), stream);

  msrp_fused<<<GRID1, BLOCK, 0, stream>>>(outp, labels, partS, partC,
                                          counter, dst, B, C);
}

// Round 4
// 356.562 us; speedup vs baseline: 1.2757x; 1.2757x over previous
//
#include <hip/hip_runtime.h>
#include <math.h>

// Multi-class SVM hinge loss + correct-count. Streaming, memory-bound.
// Floor ~30 us (132 MB HBM + ~130 MB LLC-resident at measured rates).
//  - TWO kernels. R3 showed fused finalize (per-block __threadfence +
//    same-address atomic across 2048 co-resident blocks) costs ~+95 us on
//    gfx950 (device-scope release = L2 writeback, serialized per-XCD).
//  - software pipeline across rows: issue row k+1's 4 float4 loads before
//    consuming row k -> 8 KB in flight per wave continuously, compiler can
//    wait at vmcnt(4) instead of vmcnt(0).
//  - hinge sum is lane-separable -> one wave reduce at the end.
//  - accuracy via per-row __ballot of "violation" (argmax==label iff none).
//  - labels+grounds prefetched in parallel (lane k owns row k), __shfl bcast.
//  - __launch_bounds__(256, 8) pins VGPR <= 64 -> 32 waves/CU.

#define BLOCK 256
#define GRID1 2048
#define WPB   (BLOCK / 64)            // 4 waves per block
#define NWAVE (GRID1 * WPB)           // 8192 waves = 32/CU

#define CONSUME(v, jb)                                                   \
  do {                                                                   \
    s0 += fmaxf((v).x + base, 0.0f);                                     \
    s1 += fmaxf((v).y + base, 0.0f);                                     \
    s2 += fmaxf((v).z + base, 0.0f);                                     \
    s3 += fmaxf((v).w + base, 0.0f);                                     \
    viol |= ((v).x > g) | (((v).x == g) & ((jb)     < label));           \
    viol |= ((v).y > g) | (((v).y == g) & ((jb) + 1 < label));           \
    viol |= ((v).z > g) | (((v).z == g) & ((jb) + 2 < label));           \
    viol |= ((v).w > g) | (((v).w == g) & ((jb) + 3 < label));           \
  } while (0)

__global__ __launch_bounds__(BLOCK, 8) void msrp_partial(
    const float* __restrict__ outp, const int* __restrict__ labels,
    float* __restrict__ partS, int* __restrict__ partC, int B, int C) {
  const int lane    = threadIdx.x & 63;
  const int wib     = threadIdx.x >> 6;
  const int wave_id = blockIdx.x * WPB + wib;
  const int R       = (B + NWAVE - 1) / NWAVE;   // rows per wave (8)
  const int r0      = wave_id * R;

  // Parallel prefetch: lane k holds row r0+k's label and ground score.
  int   mylab = 0;
  float myg   = 0.0f;
  if (lane < R && lane < 64 && r0 + lane < B) {
    mylab = labels[r0 + lane];
    myg   = outp[(size_t)(r0 + lane) * C + mylab];
  }

  float s0 = 0.f, s1 = 0.f, s2 = 0.f, s3 = 0.f;
  int correct = 0;                                // lane 0 only

  if (C == 1000 && r0 + R <= B) {
    // 250 float4 per row: lanes cover j = lane, +64, +128; lanes 0..57 also
    // j = lane+192. 4th load uses a clamped address (duplicate-line reads
    // broadcast for free) so all 4 loads issue unconditionally.
    const int idx3 = (lane < 58) ? lane + 192 : 249;
    const bool h3  = (lane < 58);
    const float* rowbase = outp + (size_t)r0 * 1000;

    const float4* rp = (const float4*)rowbase;
    float4 a0 = rp[lane], a1 = rp[lane + 64], a2 = rp[lane + 128], a3 = rp[idx3];

    for (int k = 0; k < R; ++k) {
      float4 b0, b1, b2, b3;
      if (k + 1 < R) {   // prefetch next row before consuming current
        const float4* rn = (const float4*)(rowbase + (size_t)(k + 1) * 1000);
        b0 = rn[lane]; b1 = rn[lane + 64]; b2 = rn[lane + 128]; b3 = rn[idx3];
      } else {
        b0 = a0; b1 = a1; b2 = a2; b3 = a3;
      }

      const int   label = __shfl(mylab, k, 64);
      const float g     = __shfl(myg, k, 64);
      const float base  = 1.0f - g;
      bool viol = false;
      CONSUME(a0, lane * 4);
      CONSUME(a1, (lane + 64) * 4);
      CONSUME(a2, (lane + 128) * 4);
      if (h3) CONSUME(a3, (lane + 192) * 4);

      const unsigned long long m = __ballot(viol);
      if (lane == 0) correct += (m == 0ULL) ? 1 : 0;

      a0 = b0; a1 = b1; a2 = b2; a3 = b3;
    }
  } else {
    const int C4 = C >> 2;
    for (int k = 0; k < R; ++k) {
      const int row = r0 + k;
      if (row >= B) break;
      const int   label = __shfl(mylab, k, 64);
      const float g     = __shfl(myg, k, 64);
      const float base  = 1.0f - g;
      const float4* rp4 = (const float4*)(outp + (size_t)row * C);
      bool viol = false;
      for (int j = lane; j < C4; j += 64) {
        float4 v = rp4[j];
        CONSUME(v, j << 2);
      }
      const float* rowp = (const float*)rp4;
      for (int j = (C4 << 2) + lane; j < C; j += 64) {
        float v = rowp[j];
        s0 += fmaxf(v + base, 0.0f);
        viol |= (v > g) | ((v == g) & (j < label));
      }
      const unsigned long long m = __ballot(viol);
      if (lane == 0) correct += (m == 0ULL) ? 1 : 0;
    }
  }

  // wave reduction of the hinge sum
  float s = (s0 + s1) + (s2 + s3);
  for (int off = 32; off > 0; off >>= 1) s += __shfl_down(s, off, 64);

  __shared__ float ls[WPB];
  __shared__ int   cs[WPB];
  if (lane == 0) { ls[wib] = s; cs[wib] = correct; }
  __syncthreads();
  if (threadIdx.x == 0) {
    float S = 0.f; int cc = 0;
    for (int w = 0; w < WPB; ++w) { S += ls[w]; cc += cs[w]; }
    partS[blockIdx.x] = S;
    partC[blockIdx.x] = cc;
  }
}

__global__ __launch_bounds__(BLOCK) void msrp_finalize(
    const float* __restrict__ partS, const int* __restrict__ partC,
    float* __restrict__ dst, int B, int nPart) {
  const int tid = threadIdx.x;
  float s = 0.0f; int c = 0;
  for (int i = tid; i < nPart; i += BLOCK) { s += partS[i]; c += partC[i]; }

  const int lane = tid & 63;
  const int wib  = tid >> 6;
  for (int off = 32; off > 0; off >>= 1) {
    s += __shfl_down(s, off, 64);
    c += __shfl_down(c, off, 64);
  }
  __shared__ float ls[WPB];
  __shared__ int   cs[WPB];
  if (lane == 0) { ls[wib] = s; cs[wib] = c; }
  __syncthreads();
  if (tid == 0) {
    float S = 0.f; int cc = 0;
    for (int w = 0; w < WPB; ++w) { S += ls[w]; cc += cs[w]; }
    // loss = (S_total - B)/B = S/B - 1 (per-row "-1" folded in)
    dst[0] = S / (float)B - 1.0f;
    dst[1] = (float)cc;
  }
}

extern "C" void kernel_launch(void* const* d_in, const int* in_sizes, int n_in,
                              void* d_out, int out_size, void* d_ws, size_t ws_size,
                              hipStream_t stream) {
  const float* outp   = (const float*)d_in[0];
  const int*   labels = (const int*)d_in[1];
  float*       dst    = (float*)d_out;

  const int B = in_sizes[1];
  const int C = in_sizes[0] / B;

  float* partS = (float*)d_ws;            // GRID1 floats
  int*   partC = (int*)(partS + GRID1);   // GRID1 ints

  msrp_partial<<<GRID1, BLOCK, 0, stream>>>(outp, labels, partS, partC, B, C);
  msrp_finalize<<<1, BLOCK, 0, stream>>>(partS, partC, dst, B, GRID1);
}